// Round 18
// baseline (847.355 us; speedup 1.0000x reference)
//
#include <hip/hip_runtime.h>
#include <math.h>

#define BATCH 16
#define IN 128
#define HD 32
#define NN 2048
#define NE 32768
#define SEQ 100
#define TPB 512
#define NBLK 512            // 2 blocks/CU -- PROVEN co-resident (rounds 6-17); do not raise
#define GSZ 32              // global barrier: blocks per group
#define NGRP (NBLK / GSZ)   // 16
#define NXCD 8
#define MAXJ 64             // max (k,wave) node slots per block
#define ECAP 1536           // LDS edge cache entries (int2, 12 KB)
#define WPITCH 34           // f32x2 pitch of transposed Wg rows (16B-aligned, conflict-free)

using f32x2 = __attribute__((ext_vector_type(2))) float;
using f32x4 = __attribute__((ext_vector_type(4))) float;

// ---------------- preprocessing ----------------

__global__ void count_deg(const int* __restrict__ src, const int* __restrict__ dst,
                          int* deg_out, int* deg_in) {
    int e = blockIdx.x * blockDim.x + threadIdx.x;
    if (e < NE) {
        atomicAdd(&deg_out[src[e]], 1);
        atomicAdd(&deg_in[dst[e]], 1);
    }
}

__global__ void scan_rowptr(const int* __restrict__ deg_in, int* __restrict__ row_ptr) {
    __shared__ int partial[256];
    int t = threadIdx.x;
    int base = t * 8;
    int vals[8];
    int s = 0;
    for (int j = 0; j < 8; j++) { vals[j] = deg_in[base + j]; s += vals[j]; }
    partial[t] = s;
    __syncthreads();
    if (t == 0) {
        int acc = 0;
        for (int i = 0; i < 256; i++) { int v = partial[i]; partial[i] = acc; acc += v; }
        row_ptr[NN] = acc;
    }
    __syncthreads();
    int acc = partial[t];
    for (int j = 0; j < 8; j++) { row_ptr[base + j] = acc; acc += vals[j]; }
}

// degree-descending permutation via counting sort (proven round 17):
// dealing perm[] round-robin equalizes per-wave edge totals AND makes
// adjacent k-strata near-equal degree (cheap pair-max equalization).
__global__ void build_perm(const int* __restrict__ deg_in, int* __restrict__ perm) {
    __shared__ int hist[64];
    __shared__ int off[64];
    int t = threadIdx.x;                 // 256 threads
    if (t < 64) hist[t] = 0;
    __syncthreads();
    for (int n = t; n < NN; n += 256) {
        int d = deg_in[n]; if (d > 63) d = 63;
        atomicAdd(&hist[d], 1);
    }
    __syncthreads();
    if (t == 0) {
        int acc = 0;
        for (int d = 63; d >= 0; d--) { off[d] = acc; acc += hist[d]; }
    }
    __syncthreads();
    for (int n = t; n < NN; n += 256) {
        int d = deg_in[n]; if (d > 63) d = 63;
        int pos = atomicAdd(&off[d], 1);
        perm[pos] = n;
    }
}

// col_idx stores src*HD (element offset of the source node's row)
__global__ void scatter_edges(const int* __restrict__ src, const int* __restrict__ dst,
                              const int* __restrict__ deg_out, const int* __restrict__ deg_in,
                              const int* __restrict__ row_ptr, int* __restrict__ cursor,
                              int* __restrict__ col_idx, float* __restrict__ wgt) {
    int e = blockIdx.x * blockDim.x + threadIdx.x;
    if (e < NE) {
        int s = src[e], d = dst[e];
        int pos = row_ptr[d] + atomicAdd(&cursor[d], 1);
        col_idx[pos] = s * HD;
        float doo = (float)max(deg_out[s], 1);
        float dii = (float)max(deg_in[d], 1);
        wgt[pos] = rsqrtf(doo * dii);
    }
}

__global__ void xgates(const float* __restrict__ x,
                       const float* __restrict__ Wr, const float* __restrict__ br,
                       const float* __restrict__ Wz, const float* __restrict__ bz,
                       const float* __restrict__ Wh, const float* __restrict__ bh,
                       float* __restrict__ xr, float* __restrict__ xz, float* __restrict__ xh) {
    int t = blockIdx.x * blockDim.x + threadIdx.x;
    if (t < BATCH * HD) {
        int b = t / HD, hh = t % HD;
        float ar = br[hh], az = bz[hh], ah = bh[hh];
        const float* xb = x + b * IN;
        for (int i = 0; i < IN; i++) {
            float xv = xb[i];
            ar += xv * Wr[i * HD + hh];
            az += xv * Wz[i * HD + hh];
            ah += xv * Wh[i * HD + hh];
        }
        xr[t] = ar; xz[t] = az; xh[t] = ah;
    }
}

// ---------------- barriers ----------------

// Global two-level barrier with agent fences (proven round 6).
__device__ __forceinline__ void global_barrier(unsigned* __restrict__ lvl1,
                                               unsigned* __restrict__ root,
                                               unsigned step) {
    __syncthreads();
    if (threadIdx.x == 0) {
        const int gid = blockIdx.x / GSZ;
        __builtin_amdgcn_fence(__ATOMIC_RELEASE, "agent");
        __hip_atomic_fetch_add(&lvl1[gid * 32], 1u, __ATOMIC_RELAXED,
                               __HIP_MEMORY_SCOPE_AGENT);
        if ((blockIdx.x % GSZ) == 0) {
            while (__hip_atomic_load(&lvl1[gid * 32], __ATOMIC_RELAXED,
                                     __HIP_MEMORY_SCOPE_AGENT) < GSZ * step)
                __builtin_amdgcn_s_sleep(2);
            __hip_atomic_fetch_add(root, 1u, __ATOMIC_RELAXED,
                                   __HIP_MEMORY_SCOPE_AGENT);
        }
        while (__hip_atomic_load(root, __ATOMIC_RELAXED,
                                 __HIP_MEMORY_SCOPE_AGENT) < NGRP * step)
            __builtin_amdgcn_s_sleep(2);
        __builtin_amdgcn_fence(__ATOMIC_ACQUIRE, "agent");
    }
    __syncthreads();
}

// Per-XCD barrier (proven rounds 7-17). Arrivals spread over 8 cache lines
// (slot&7); leader polls the 8-line sum (monotonic counters -> race-free).
__device__ __forceinline__ void xcd_barrier(unsigned* __restrict__ xcnt,
                                            unsigned* __restrict__ xgo,
                                            int xid, int slot, int cnt, unsigned s) {
    __syncthreads();
    if (threadIdx.x == 0) {
        __hip_atomic_fetch_add(&xcnt[(xid * 8 + (slot & 7)) * 32], 1u,
                               __ATOMIC_RELAXED, __HIP_MEMORY_SCOPE_AGENT);
        if (slot == 0) {
            for (;;) {
                unsigned sum = 0;
#pragma unroll
                for (int i = 0; i < 8; i++)
                    sum += __hip_atomic_load(&xcnt[(xid * 8 + i) * 32],
                                             __ATOMIC_RELAXED, __HIP_MEMORY_SCOPE_AGENT);
                if (sum >= (unsigned)cnt * s) break;
                __builtin_amdgcn_s_sleep(1);
            }
            __hip_atomic_store(&xgo[xid * 32], s, __ATOMIC_RELAXED,
                               __HIP_MEMORY_SCOPE_AGENT);
        } else {
            while (__hip_atomic_load(&xgo[xid * 32], __ATOMIC_RELAXED,
                                     __HIP_MEMORY_SCOPE_AGENT) < s)
                __builtin_amdgcn_s_sleep(1);
        }
    }
    __syncthreads();
    asm volatile("buffer_inv sc0\n\ts_waitcnt vmcnt(0)" ::: "memory");
}

// ---------------- persistent kernel ----------------
// h layout: [B][N][H] in a compact 4MB double buffer (L2-resident).
// Lane map: wave = TWO nodes (half-wave each); within a half-wave 2 batches
// x 16 lanes; each lane owns 2 adjacent channels as f32x2 -> ~40% fewer
// instructions than scalar. Gather: 16-edge chunks (16 loads in flight,
// proven depth). Wg lives in a transposed LDS tile -- NOT registers (round
// 15's spill source: wgreg2 was 64 VGPR over the 128 co-residency cap).

__device__ __forceinline__ float fast_sigmoid(float x) {
    return __builtin_amdgcn_rcpf(1.f + __expf(-x));
}

// GRU gates on a channel pair
__device__ __forceinline__ f32x2 gru_gate2(f32x2 conv, f32x2 xr2, f32x2 xz2,
                                           f32x2 xh2, f32x2 hp) {
    f32x2 hn;
    {
        float r = fast_sigmoid(xr2.x + conv.x);
        float z = fast_sigmoid(xz2.x + conv.x);
        float e2 = __expf(2.f * (xh2.x + r * conv.x));
        float ht = 1.f - 2.f * __builtin_amdgcn_rcpf(e2 + 1.f);
        hn.x = fmaf(z, ht - hp.x, hp.x);
    }
    {
        float r = fast_sigmoid(xr2.y + conv.y);
        float z = fast_sigmoid(xz2.y + conv.y);
        float e2 = __expf(2.f * (xh2.y + r * conv.y));
        float ht = 1.f - 2.f * __builtin_amdgcn_rcpf(e2 + 1.f);
        hn.y = fmaf(z, ht - hp.y, hp.y);
    }
    return hn;
}

__global__ void __launch_bounds__(TPB, 4) gru_persistent(
    float* __restrict__ hA, float* __restrict__ hB,
    const int* __restrict__ row_ptr, const int* __restrict__ col_idx,
    const float* __restrict__ wgt, const int* __restrict__ perm,
    const float* __restrict__ Wg, const float* __restrict__ bg,
    const float* __restrict__ xr, const float* __restrict__ xz,
    const float* __restrict__ xh,
    float* __restrict__ out,
    unsigned* __restrict__ glvl1, unsigned* __restrict__ groot,
    unsigned* __restrict__ xreg, unsigned* __restrict__ xcnt,
    unsigned* __restrict__ xgo)
{
    __shared__ f32x2 aggL2[TPB];
    __shared__ __align__(16) f32x2 wgT[16 * WPITCH];   // wgT[cp*WPITCH+k] = Wg[k][2cp..2cp+1]
    __shared__ int jn[MAXJ], jrs[MAXJ], jraw[MAXJ], jplen[MAXJ], jofs[MAXJ];
    __shared__ __align__(16) int2 eLDS[ECAP];   // (byte-offset, bitcast weight)
    __shared__ int shr_slot, shr_cnt, shr_mode, shr_use;

    const int tid = threadIdx.x;
    const int lane = tid & 63;
    const int wid = tid >> 6;        // wave id (0..7)
    const int half = lane >> 5;      // which node of the pair
    const int bi = (lane >> 4) & 1;  // which batch of the XCD's pair
    const int cp = lane & 15;        // channel-pair index: channels 2cp, 2cp+1

    // physical XCD id [measured: learn_hip m09]
    int xraw;
    asm volatile("s_getreg_b32 %0, hwreg(HW_REG_XCC_ID)" : "=s"(xraw));
    int xid = xraw & 7;

    if (tid == 0)
        shr_slot = (int)__hip_atomic_fetch_add(&xreg[xid * 32], 1u, __ATOMIC_RELAXED,
                                               __HIP_MEMORY_SCOPE_AGENT);
    __syncthreads();
    int slot = shr_slot;

    global_barrier(glvl1, groot, 1u);   // settle registration

    if (tid == 0) {
        int sum = 0, mode = 1, mycnt = 0;
        for (int xx = 0; xx < NXCD; xx++) {
            int c = (int)__hip_atomic_load(&xreg[xx * 32], __ATOMIC_RELAXED,
                                           __HIP_MEMORY_SCOPE_AGENT);
            sum += c;
            if (c < 32) mode = 0;       // guarantees nodes/wave <= 8 (MAXJ)
            if (xx == xid) mycnt = c;
        }
        if (sum != NBLK) mode = 0;
        shr_mode = mode;
        shr_cnt = mycnt;
    }
    __syncthreads();
    const int xmode = shr_mode;
    int cnt = shr_cnt;
    if (!xmode) { xid = blockIdx.x & 7; slot = blockIdx.x >> 3; cnt = NBLK / NXCD; }
    const int wtot = cnt * 8;

    // ---- stage transposed Wg into LDS (time-invariant) ----
    {
        int idx = tid;                   // 512 entries: k=idx&31, cp2=idx>>5
        int k = idx & 31, cp2 = idx >> 5;
        f32x2 w;
        w.x = Wg[k * HD + 2 * cp2];
        w.y = Wg[k * HD + 2 * cp2 + 1];
        wgT[cp2 * WPITCH + k] = w;
    }

    // ---- per-block node metadata (j = k*8 + waveid), degree-balanced ----
    if (tid < MAXJ) {
        int k = tid >> 3, w = tid & 7;
        int idx = slot * 8 + w + k * wtot;
        if (idx < NN) {
            int n = perm[idx];
            int rs = row_ptr[n], re = row_ptr[n + 1];
            jn[tid] = n; jrs[tid] = rs; jraw[tid] = re - rs;
            jplen[tid] = (re - rs + 7) & ~7;
        } else {
            jn[tid] = -1; jrs[tid] = 0; jraw[tid] = 0; jplen[tid] = 0;
        }
    }
    __syncthreads();
    // pair-equalize (k,k+1) so both half-waves run the same trip count.
    // degree-sorted perm makes adjacent strata near-equal -> pad cost tiny.
    int pmax = 0;
    if (tid < MAXJ) pmax = max(jplen[tid], jplen[tid ^ 8]);
    __syncthreads();
    if (tid < MAXJ && jn[tid] >= 0) jplen[tid] = pmax;
    __syncthreads();
    if (tid == 0) {
        int o = 0;
        for (int j = 0; j < MAXJ; j++) { jofs[j] = o; o += jplen[j]; }
        shr_use = (o <= ECAP);
    }
    __syncthreads();
    const bool use_lds = (shr_use != 0);

    // ---- stage edges into LDS once (time-invariant), zero-padded ----
    if (use_lds) {
        for (int k = 0; k < 8; k++) {
            int j = k * 8 + wid;
            if (jn[j] < 0) break;
            int rs = jrs[j], raw = jraw[j], pl = jplen[j], of = jofs[j];
            for (int i = lane; i < pl; i += 64) {
                int2 v;
                if (i < raw) { v.x = col_idx[rs + i] << 2; v.y = __float_as_int(wgt[rs + i]); }
                else         { v.x = 0; v.y = 0; }
                eLDS[of + i] = v;
            }
        }
    }
    __syncthreads();

    // ---- per-thread constants ----
    const int bb = 2 * xid + bi;
    const f32x2 xr2 = *(const f32x2*)&xr[bb * HD + 2 * cp];
    const f32x2 xz2 = *(const f32x2*)&xz[bb * HD + 2 * cp];
    const f32x2 xh2 = *(const f32x2*)&xh[bb * HD + 2 * cp];
    const f32x2 bg2 = *(const f32x2*)&bg[2 * cp];

    const int hoffb = bb * (NN * HD) * 4 + cp * 8;     // byte offset of this lane's pair
    float* outp = out + (size_t)bb * SEQ * (NN * HD) + 2 * cp;

    const char* hprev = (const char*)hA;
    char* hnext = (char*)hB;

    // ---- t = 0: state is identically zero -> no gather, no matvec, no h-read ----
    {
        f32x2 zero2; zero2.x = 0.f; zero2.y = 0.f;
        const f32x2 hn2 = gru_gate2(bg2, xr2, xz2, xh2, zero2);
        for (int p = 0; p < 4; p++) {
            const int n = jn[(2 * p + half) * 8 + wid];
            if (n >= 0) {
                *(f32x2*)(hnext + (hoffb + (n << 7))) = hn2;
                __builtin_nontemporal_store(hn2, (f32x2*)(outp + n * HD));
            }
        }
    }
    if (xmode) xcd_barrier(xcnt, xgo, xid, slot, cnt, 1u);
    else       global_barrier(glvl1, groot, 2u);
    { char* tmp = (char*)hprev; hprev = hnext; hnext = tmp; }
    outp += NN * HD;

    for (int t = 1; t < SEQ; t++) {
        for (int p = 0; p < 4; p++) {
            const int jj = (2 * p + half) * 8 + wid;   // half selects the node
            const int n = jn[jj];
            const int pl = jplen[jj];

            f32x2 agg2; agg2.x = 0.f; agg2.y = 0.f;
            if (use_lds) {
                const int4* ep = (const int4*)&eLDS[jofs[jj]];   // 2 edges per int4
                int e = 0;
                // 16-edge main chunk: 16 f32x2 loads in flight (proven depth)
                for (; e + 16 <= pl; e += 16) {
                    int4 q0 = ep[0], q1 = ep[1], q2 = ep[2], q3 = ep[3];
                    int4 q4 = ep[4], q5 = ep[5], q6 = ep[6], q7 = ep[7];
                    ep += 8;
                    f32x2 v0 = *(const f32x2*)(hprev + (hoffb + q0.x));
                    f32x2 v1 = *(const f32x2*)(hprev + (hoffb + q0.z));
                    f32x2 v2 = *(const f32x2*)(hprev + (hoffb + q1.x));
                    f32x2 v3 = *(const f32x2*)(hprev + (hoffb + q1.z));
                    f32x2 v4 = *(const f32x2*)(hprev + (hoffb + q2.x));
                    f32x2 v5 = *(const f32x2*)(hprev + (hoffb + q2.z));
                    f32x2 v6 = *(const f32x2*)(hprev + (hoffb + q3.x));
                    f32x2 v7 = *(const f32x2*)(hprev + (hoffb + q3.z));
                    f32x2 v8 = *(const f32x2*)(hprev + (hoffb + q4.x));
                    f32x2 v9 = *(const f32x2*)(hprev + (hoffb + q4.z));
                    f32x2 va = *(const f32x2*)(hprev + (hoffb + q5.x));
                    f32x2 vb = *(const f32x2*)(hprev + (hoffb + q5.z));
                    f32x2 vc = *(const f32x2*)(hprev + (hoffb + q6.x));
                    f32x2 vd = *(const f32x2*)(hprev + (hoffb + q6.z));
                    f32x2 ve = *(const f32x2*)(hprev + (hoffb + q7.x));
                    f32x2 vf = *(const f32x2*)(hprev + (hoffb + q7.z));
                    float w0 = __int_as_float(q0.y), w1 = __int_as_float(q0.w);
                    float w2 = __int_as_float(q1.y), w3 = __int_as_float(q1.w);
                    float w4 = __int_as_float(q2.y), w5 = __int_as_float(q2.w);
                    float w6 = __int_as_float(q3.y), w7 = __int_as_float(q3.w);
                    float w8 = __int_as_float(q4.y), w9 = __int_as_float(q4.w);
                    float wa = __int_as_float(q5.y), wb = __int_as_float(q5.w);
                    float wc = __int_as_float(q6.y), wd = __int_as_float(q6.w);
                    float we = __int_as_float(q7.y), wf = __int_as_float(q7.w);
                    agg2.x = fmaf(w0, v0.x, agg2.x); agg2.y = fmaf(w0, v0.y, agg2.y);
                    agg2.x = fmaf(w1, v1.x, agg2.x); agg2.y = fmaf(w1, v1.y, agg2.y);
                    agg2.x = fmaf(w2, v2.x, agg2.x); agg2.y = fmaf(w2, v2.y, agg2.y);
                    agg2.x = fmaf(w3, v3.x, agg2.x); agg2.y = fmaf(w3, v3.y, agg2.y);
                    agg2.x = fmaf(w4, v4.x, agg2.x); agg2.y = fmaf(w4, v4.y, agg2.y);
                    agg2.x = fmaf(w5, v5.x, agg2.x); agg2.y = fmaf(w5, v5.y, agg2.y);
                    agg2.x = fmaf(w6, v6.x, agg2.x); agg2.y = fmaf(w6, v6.y, agg2.y);
                    agg2.x = fmaf(w7, v7.x, agg2.x); agg2.y = fmaf(w7, v7.y, agg2.y);
                    agg2.x = fmaf(w8, v8.x, agg2.x); agg2.y = fmaf(w8, v8.y, agg2.y);
                    agg2.x = fmaf(w9, v9.x, agg2.x); agg2.y = fmaf(w9, v9.y, agg2.y);
                    agg2.x = fmaf(wa, va.x, agg2.x); agg2.y = fmaf(wa, va.y, agg2.y);
                    agg2.x = fmaf(wb, vb.x, agg2.x); agg2.y = fmaf(wb, vb.y, agg2.y);
                    agg2.x = fmaf(wc, vc.x, agg2.x); agg2.y = fmaf(wc, vc.y, agg2.y);
                    agg2.x = fmaf(wd, vd.x, agg2.x); agg2.y = fmaf(wd, vd.y, agg2.y);
                    agg2.x = fmaf(we, ve.x, agg2.x); agg2.y = fmaf(we, ve.y, agg2.y);
                    agg2.x = fmaf(wf, vf.x, agg2.x); agg2.y = fmaf(wf, vf.y, agg2.y);
                }
                if (e < pl) {   // pl multiple of 8 -> at most one 8-edge tail
                    int4 q0 = ep[0], q1 = ep[1], q2 = ep[2], q3 = ep[3];
                    f32x2 v0 = *(const f32x2*)(hprev + (hoffb + q0.x));
                    f32x2 v1 = *(const f32x2*)(hprev + (hoffb + q0.z));
                    f32x2 v2 = *(const f32x2*)(hprev + (hoffb + q1.x));
                    f32x2 v3 = *(const f32x2*)(hprev + (hoffb + q1.z));
                    f32x2 v4 = *(const f32x2*)(hprev + (hoffb + q2.x));
                    f32x2 v5 = *(const f32x2*)(hprev + (hoffb + q2.z));
                    f32x2 v6 = *(const f32x2*)(hprev + (hoffb + q3.x));
                    f32x2 v7 = *(const f32x2*)(hprev + (hoffb + q3.z));
                    float w0 = __int_as_float(q0.y), w1 = __int_as_float(q0.w);
                    float w2 = __int_as_float(q1.y), w3 = __int_as_float(q1.w);
                    float w4 = __int_as_float(q2.y), w5 = __int_as_float(q2.w);
                    float w6 = __int_as_float(q3.y), w7 = __int_as_float(q3.w);
                    agg2.x = fmaf(w0, v0.x, agg2.x); agg2.y = fmaf(w0, v0.y, agg2.y);
                    agg2.x = fmaf(w1, v1.x, agg2.x); agg2.y = fmaf(w1, v1.y, agg2.y);
                    agg2.x = fmaf(w2, v2.x, agg2.x); agg2.y = fmaf(w2, v2.y, agg2.y);
                    agg2.x = fmaf(w3, v3.x, agg2.x); agg2.y = fmaf(w3, v3.y, agg2.y);
                    agg2.x = fmaf(w4, v4.x, agg2.x); agg2.y = fmaf(w4, v4.y, agg2.y);
                    agg2.x = fmaf(w5, v5.x, agg2.x); agg2.y = fmaf(w5, v5.y, agg2.y);
                    agg2.x = fmaf(w6, v6.x, agg2.x); agg2.y = fmaf(w6, v6.y, agg2.y);
                    agg2.x = fmaf(w7, v7.x, agg2.x); agg2.y = fmaf(w7, v7.y, agg2.y);
                }
            } else {   // rare overflow path: stream edge list from global
                const int rs = jrs[jj], re = rs + jraw[jj];
                for (int e = rs; e < re; e++) {
                    int cb = col_idx[e] << 2;
                    float w = wgt[e];
                    f32x2 v = *(const f32x2*)(hprev + (hoffb + cb));
                    agg2.x = fmaf(w, v.x, agg2.x);
                    agg2.y = fmaf(w, v.y, agg2.y);
                }
            }

            // matvec: conv[2cp..2cp+1] = bg + sum_k agg[k] * Wg[k][2cp..2cp+1]
            // agg shared by the 16-lane group via LDS (wave-lockstep);
            // Wg read from the transposed LDS tile (b128, conflict-free).
            aggL2[tid] = agg2;
            const f32x4* arow = (const f32x4*)((const float*)aggL2 + (tid & ~15) * 2);
            const f32x2* wrow = &wgT[cp * WPITCH];
            f32x2 conv2 = bg2;
#pragma unroll
            for (int kq = 0; kq < 8; kq++) {
                f32x4 a4 = arow[kq];
                f32x4 w01 = *(const f32x4*)&wrow[4 * kq];       // k=4kq, 4kq+1
                f32x4 w23 = *(const f32x4*)&wrow[4 * kq + 2];   // k=4kq+2, 4kq+3
                conv2.x = fmaf(a4.x, w01.x, conv2.x); conv2.y = fmaf(a4.x, w01.y, conv2.y);
                conv2.x = fmaf(a4.y, w01.z, conv2.x); conv2.y = fmaf(a4.y, w01.w, conv2.y);
                conv2.x = fmaf(a4.z, w23.x, conv2.x); conv2.y = fmaf(a4.z, w23.y, conv2.y);
                conv2.x = fmaf(a4.w, w23.z, conv2.x); conv2.y = fmaf(a4.w, w23.w, conv2.y);
            }

            if (n >= 0) {
                const int nb = hoffb + (n << 7);
                const f32x2 hp2 = *(const f32x2*)(hprev + nb);
                const f32x2 hn2 = gru_gate2(conv2, xr2, xz2, xh2, hp2);
                *(f32x2*)(hnext + nb) = hn2;
                __builtin_nontemporal_store(hn2, (f32x2*)(outp + n * HD));
            }
        }

        if (t != SEQ - 1) {
            if (xmode) xcd_barrier(xcnt, xgo, xid, slot, cnt, (unsigned)(t + 1));
            else       global_barrier(glvl1, groot, (unsigned)(t + 2));
        }
        char* tmp = (char*)hprev; hprev = hnext; hnext = tmp;
        outp += NN * HD;
    }
}

// ---------------- launch ----------------

extern "C" void kernel_launch(void* const* d_in, const int* in_sizes, int n_in,
                              void* d_out, int out_size, void* d_ws, size_t ws_size,
                              hipStream_t stream) {
    const float* x   = (const float*)d_in[0];
    const int*   src = (const int*)d_in[1];
    const int*   dst = (const int*)d_in[2];
    const float* Wr  = (const float*)d_in[3];
    const float* br  = (const float*)d_in[4];
    const float* Wz  = (const float*)d_in[5];
    const float* bz  = (const float*)d_in[6];
    const float* Wh  = (const float*)d_in[7];
    const float* bh  = (const float*)d_in[8];
    const float* Wg  = (const float*)d_in[9];
    const float* bg  = (const float*)d_in[10];
    float* out = (float*)d_out;

    char* ws = (char*)d_ws;
    float* h0 = (float*)ws;            ws += (size_t)BATCH * NN * HD * 4;
    float* h1 = (float*)ws;            ws += (size_t)BATCH * NN * HD * 4;
    float* xr = (float*)ws;            ws += BATCH * HD * 4;
    float* xz = (float*)ws;            ws += BATCH * HD * 4;
    float* xh = (float*)ws;            ws += BATCH * HD * 4;
    int* deg_out = (int*)ws;           ws += NN * 4;
    int* deg_in  = (int*)ws;           ws += NN * 4;
    int* cursor  = (int*)ws;           ws += NN * 4;
    int* row_ptr = (int*)ws;           ws += (NN + 1) * 4;
    int* col_idx = (int*)ws;           ws += NE * 4;
    float* wgt   = (float*)ws;         ws += NE * 4;
    int* perm    = (int*)ws;           ws += NN * 4;
    unsigned* glvl1 = (unsigned*)ws;   ws += NGRP * 32 * 4;
    unsigned* groot = (unsigned*)ws;   ws += 32 * 4;
    unsigned* xreg  = (unsigned*)ws;   ws += NXCD * 32 * 4;
    unsigned* xcnt  = (unsigned*)ws;   ws += NXCD * 8 * 32 * 4;
    unsigned* xgo   = (unsigned*)ws;   ws += NXCD * 32 * 4;

    // t=0 shortcut never reads h -> no h memset needed; only barrier counters.
    hipMemsetAsync(deg_out, 0, 3 * NN * 4, stream);
    hipMemsetAsync(glvl1, 0,
                   (NGRP * 32 + 32 + NXCD * 32 + NXCD * 8 * 32 + NXCD * 32) * 4, stream);

    count_deg<<<NE / 256, 256, 0, stream>>>(src, dst, deg_out, deg_in);
    scan_rowptr<<<1, 256, 0, stream>>>(deg_in, row_ptr);
    build_perm<<<1, 256, 0, stream>>>(deg_in, perm);
    scatter_edges<<<NE / 256, 256, 0, stream>>>(src, dst, deg_out, deg_in, row_ptr,
                                                cursor, col_idx, wgt);
    xgates<<<2, 256, 0, stream>>>(x, Wr, br, Wz, bz, Wh, bh, xr, xz, xh);

    gru_persistent<<<dim3(NBLK), dim3(TPB), 0, stream>>>(
        h0, h1, row_ptr, col_idx, wgt, perm, Wg, bg, xr, xz, xh, out,
        glvl1, groot, xreg, xcnt, xgo);
}

// Round 19
// 726.626 us; speedup vs baseline: 1.1662x; 1.1662x over previous
//
#include <hip/hip_runtime.h>
#include <math.h>

#define BATCH 16
#define IN 128
#define HD 32
#define NN 2048
#define NE 32768
#define SEQ 100
#define TPB 512
#define NBLK 512            // 2 blocks/CU -- PROVEN co-resident (rounds 6-18); do not raise
#define GSZ 32              // global barrier: blocks per group
#define NGRP (NBLK / GSZ)   // 16
#define NXCD 8
#define MAXJ 64             // max (k,wave) node slots per block
#define ECAP 1536           // LDS edge cache entries (int2, 12 KB)

// ---------------- preprocessing ----------------

__global__ void count_deg(const int* __restrict__ src, const int* __restrict__ dst,
                          int* deg_out, int* deg_in) {
    int e = blockIdx.x * blockDim.x + threadIdx.x;
    if (e < NE) {
        atomicAdd(&deg_out[src[e]], 1);
        atomicAdd(&deg_in[dst[e]], 1);
    }
}

__global__ void scan_rowptr(const int* __restrict__ deg_in, int* __restrict__ row_ptr) {
    __shared__ int partial[256];
    int t = threadIdx.x;
    int base = t * 8;
    int vals[8];
    int s = 0;
    for (int j = 0; j < 8; j++) { vals[j] = deg_in[base + j]; s += vals[j]; }
    partial[t] = s;
    __syncthreads();
    if (t == 0) {
        int acc = 0;
        for (int i = 0; i < 256; i++) { int v = partial[i]; partial[i] = acc; acc += v; }
        row_ptr[NN] = acc;
    }
    __syncthreads();
    int acc = partial[t];
    for (int j = 0; j < 8; j++) { row_ptr[base + j] = acc; acc += vals[j]; }
}

// degree-descending permutation via counting sort (64 bins, one block).
// Dealing perm[] round-robin to waves equalizes per-wave edge totals:
// the per-step barrier waits for the SLOWEST wave, so balance = speed.
__global__ void build_perm(const int* __restrict__ deg_in, int* __restrict__ perm) {
    __shared__ int hist[64];
    __shared__ int off[64];
    int t = threadIdx.x;                 // 256 threads
    if (t < 64) hist[t] = 0;
    __syncthreads();
    for (int n = t; n < NN; n += 256) {
        int d = deg_in[n]; if (d > 63) d = 63;
        atomicAdd(&hist[d], 1);
    }
    __syncthreads();
    if (t == 0) {
        int acc = 0;
        for (int d = 63; d >= 0; d--) { off[d] = acc; acc += hist[d]; }
    }
    __syncthreads();
    for (int n = t; n < NN; n += 256) {
        int d = deg_in[n]; if (d > 63) d = 63;
        int pos = atomicAdd(&off[d], 1);
        perm[pos] = n;
    }
}

// col_idx stores src*HD (element offset of the source node's row)
__global__ void scatter_edges(const int* __restrict__ src, const int* __restrict__ dst,
                              const int* __restrict__ deg_out, const int* __restrict__ deg_in,
                              const int* __restrict__ row_ptr, int* __restrict__ cursor,
                              int* __restrict__ col_idx, float* __restrict__ wgt) {
    int e = blockIdx.x * blockDim.x + threadIdx.x;
    if (e < NE) {
        int s = src[e], d = dst[e];
        int pos = row_ptr[d] + atomicAdd(&cursor[d], 1);
        col_idx[pos] = s * HD;
        float doo = (float)max(deg_out[s], 1);
        float dii = (float)max(deg_in[d], 1);
        wgt[pos] = rsqrtf(doo * dii);
    }
}

__global__ void xgates(const float* __restrict__ x,
                       const float* __restrict__ Wr, const float* __restrict__ br,
                       const float* __restrict__ Wz, const float* __restrict__ bz,
                       const float* __restrict__ Wh, const float* __restrict__ bh,
                       float* __restrict__ xr, float* __restrict__ xz, float* __restrict__ xh) {
    int t = blockIdx.x * blockDim.x + threadIdx.x;
    if (t < BATCH * HD) {
        int b = t / HD, hh = t % HD;
        float ar = br[hh], az = bz[hh], ah = bh[hh];
        const float* xb = x + b * IN;
        for (int i = 0; i < IN; i++) {
            float xv = xb[i];
            ar += xv * Wr[i * HD + hh];
            az += xv * Wz[i * HD + hh];
            ah += xv * Wh[i * HD + hh];
        }
        xr[t] = ar; xz[t] = az; xh[t] = ah;
    }
}

// ---------------- barriers ----------------

// Global two-level barrier with agent fences (proven round 6).
__device__ __forceinline__ void global_barrier(unsigned* __restrict__ lvl1,
                                               unsigned* __restrict__ root,
                                               unsigned step) {
    __syncthreads();
    if (threadIdx.x == 0) {
        const int gid = blockIdx.x / GSZ;
        __builtin_amdgcn_fence(__ATOMIC_RELEASE, "agent");
        __hip_atomic_fetch_add(&lvl1[gid * 32], 1u, __ATOMIC_RELAXED,
                               __HIP_MEMORY_SCOPE_AGENT);
        if ((blockIdx.x % GSZ) == 0) {
            while (__hip_atomic_load(&lvl1[gid * 32], __ATOMIC_RELAXED,
                                     __HIP_MEMORY_SCOPE_AGENT) < GSZ * step)
                __builtin_amdgcn_s_sleep(2);
            __hip_atomic_fetch_add(root, 1u, __ATOMIC_RELAXED,
                                   __HIP_MEMORY_SCOPE_AGENT);
        }
        while (__hip_atomic_load(root, __ATOMIC_RELAXED,
                                 __HIP_MEMORY_SCOPE_AGENT) < NGRP * step)
            __builtin_amdgcn_s_sleep(2);
        __builtin_amdgcn_fence(__ATOMIC_ACQUIRE, "agent");
    }
    __syncthreads();
}

// Per-XCD barrier (proven rounds 7-18). Arrivals spread over 8 cache lines
// (slot&7); leader polls the 8-line sum (monotonic counters -> race-free).
__device__ __forceinline__ void xcd_barrier(unsigned* __restrict__ xcnt,
                                            unsigned* __restrict__ xgo,
                                            int xid, int slot, int cnt, unsigned s) {
    __syncthreads();
    if (threadIdx.x == 0) {
        __hip_atomic_fetch_add(&xcnt[(xid * 8 + (slot & 7)) * 32], 1u,
                               __ATOMIC_RELAXED, __HIP_MEMORY_SCOPE_AGENT);
        if (slot == 0) {
            for (;;) {
                unsigned sum = 0;
#pragma unroll
                for (int i = 0; i < 8; i++)
                    sum += __hip_atomic_load(&xcnt[(xid * 8 + i) * 32],
                                             __ATOMIC_RELAXED, __HIP_MEMORY_SCOPE_AGENT);
                if (sum >= (unsigned)cnt * s) break;
                __builtin_amdgcn_s_sleep(1);
            }
            __hip_atomic_store(&xgo[xid * 32], s, __ATOMIC_RELAXED,
                               __HIP_MEMORY_SCOPE_AGENT);
        } else {
            while (__hip_atomic_load(&xgo[xid * 32], __ATOMIC_RELAXED,
                                     __HIP_MEMORY_SCOPE_AGENT) < s)
                __builtin_amdgcn_s_sleep(1);
        }
    }
    __syncthreads();
    asm volatile("buffer_inv sc0\n\ts_waitcnt vmcnt(0)" ::: "memory");
}

// ---------------- persistent kernel ----------------
// h layout: [B][N][H] in a compact 4MB double buffer (L2-resident; round 11
// proved using `out` as state costs 200MB of HBM re-fetch).
// Wave = one node for a batch PAIR: lanes 0-31 -> batch b0, lanes 32-63 -> b0+1.
// Gather: 16-edge chunks = 16 loads in flight (rounds 12/14/18: shallower or
// restructured regresses). Scalar f32 lanes (rounds 14/15/18: float2 remap is
// latency- or spill-bound in every variant). Node->wave via degree-sorted
// perm (round 17: balanced waves, +4%).

__device__ __forceinline__ float fast_sigmoid(float x) {
    return __builtin_amdgcn_rcpf(1.f + __expf(-x));
}

__global__ void __launch_bounds__(TPB) gru_persistent(
    float* __restrict__ hA, float* __restrict__ hB,
    const int* __restrict__ row_ptr, const int* __restrict__ col_idx,
    const float* __restrict__ wgt, const int* __restrict__ perm,
    const float* __restrict__ Wg, const float* __restrict__ bg,
    const float* __restrict__ xr, const float* __restrict__ xz,
    const float* __restrict__ xh,
    float* __restrict__ out,
    unsigned* __restrict__ glvl1, unsigned* __restrict__ groot,
    unsigned* __restrict__ xreg, unsigned* __restrict__ xcnt,
    unsigned* __restrict__ xgo)
{
    __shared__ float aggL[TPB];
    __shared__ int jn[MAXJ], jrs[MAXJ], jraw[MAXJ], jplen[MAXJ], jofs[MAXJ];
    __shared__ __align__(16) int2 eLDS[ECAP];   // (byte-offset, bitcast weight)
    __shared__ int shr_slot, shr_cnt, shr_mode, shr_use;

    const int tid = threadIdx.x;
    const int lane = tid & 63;
    const int wid = tid >> 6;        // wave id (0..7)
    const int half = lane >> 5;      // which batch of the pair
    const int l = lane & 31;         // channel

    // physical XCD id [measured: learn_hip m09]
    int xraw;
    asm volatile("s_getreg_b32 %0, hwreg(HW_REG_XCC_ID)" : "=s"(xraw));
    int xid = xraw & 7;

    if (tid == 0)
        shr_slot = (int)__hip_atomic_fetch_add(&xreg[xid * 32], 1u, __ATOMIC_RELAXED,
                                               __HIP_MEMORY_SCOPE_AGENT);
    __syncthreads();
    int slot = shr_slot;

    global_barrier(glvl1, groot, 1u);   // settle registration

    if (tid == 0) {
        int sum = 0, mode = 1, mycnt = 0;
        for (int xx = 0; xx < NXCD; xx++) {
            int c = (int)__hip_atomic_load(&xreg[xx * 32], __ATOMIC_RELAXED,
                                           __HIP_MEMORY_SCOPE_AGENT);
            sum += c;
            if (c < 32) mode = 0;       // guarantees nodes/wave <= 8 (MAXJ)
            if (xx == xid) mycnt = c;
        }
        if (sum != NBLK) mode = 0;
        shr_mode = mode;
        shr_cnt = mycnt;
    }
    __syncthreads();
    const int xmode = shr_mode;
    int cnt = shr_cnt;
    if (!xmode) { xid = blockIdx.x & 7; slot = blockIdx.x >> 3; cnt = NBLK / NXCD; }
    const int wtot = cnt * 8;

    // ---- per-block node metadata (j = k*8 + waveid) ----
    // node = perm[wave + k*wtot]: degree-sorted striping -> each wave draws
    // one node per degree-stratum -> per-wave edge totals equalized.
    if (tid < MAXJ) {
        int k = tid >> 3, w = tid & 7;
        int idx = slot * 8 + w + k * wtot;
        if (idx < NN) {
            int n = perm[idx];
            int rs = row_ptr[n], re = row_ptr[n + 1];
            jn[tid] = n; jrs[tid] = rs; jraw[tid] = re - rs;
            jplen[tid] = (re - rs + 7) & ~7;
        } else {
            jn[tid] = -1; jrs[tid] = 0; jraw[tid] = 0; jplen[tid] = 0;
        }
    }
    __syncthreads();
    if (tid == 0) {
        int o = 0;
        for (int j = 0; j < MAXJ; j++) { jofs[j] = o; o += jplen[j]; }
        shr_use = (o <= ECAP);
    }
    __syncthreads();
    const bool use_lds = (shr_use != 0);

    // ---- stage edges into LDS once (time-invariant), padded to x8 ----
    if (use_lds) {
        for (int k = 0; k < 8; k++) {
            int j = k * 8 + wid;
            if (jn[j] < 0) break;
            int rs = jrs[j], raw = jraw[j], pl = jplen[j], of = jofs[j];
            for (int i = lane; i < pl; i += 64) {
                int2 v;
                if (i < raw) { v.x = col_idx[rs + i] << 2; v.y = __float_as_int(wgt[rs + i]); }
                else         { v.x = 0; v.y = 0; }
                eLDS[of + i] = v;
            }
        }
    }
    __syncthreads();

    // ---- per-thread constants ----
    const int bb = 2 * xid + half;
    const float xrv = xr[bb * HD + l];
    const float xzv = xz[bb * HD + l];
    const float xhv = xh[bb * HD + l];
    const float bgv = bg[l];
    float wgreg[HD];
#pragma unroll
    for (int k = 0; k < HD; k++) wgreg[k] = Wg[k * HD + l];

    const int hoffb = (bb * (NN * HD) + l) * 4;         // byte offset of this thread's lane
    float* outp = out + (size_t)bb * SEQ * (NN * HD) + l;

    const char* hprev = (const char*)hA;
    char* hnext = (char*)hB;

    // ---- t = 0: state is identically zero -> no gather, no matvec, no h-read ----
    {
        const float conv = bgv;
        const float r = fast_sigmoid(xrv + conv);
        const float z = fast_sigmoid(xzv + conv);
        const float e2 = __expf(2.f * (xhv + r * conv));
        const float ht = 1.f - 2.f * __builtin_amdgcn_rcpf(e2 + 1.f);
        const float hn = z * ht;                        // hp = 0
        for (int k = 0; k < 8; k++) {
            const int n = jn[k * 8 + wid];
            if (n < 0) break;
            *(float*)(hnext + (hoffb + (n << 7))) = hn;
            __builtin_nontemporal_store(hn, outp + (n << 5));
        }
    }
    if (xmode) xcd_barrier(xcnt, xgo, xid, slot, cnt, 1u);
    else       global_barrier(glvl1, groot, 2u);
    { char* tmp = (char*)hprev; hprev = hnext; hnext = tmp; }
    outp += NN * HD;

    for (int t = 1; t < SEQ; t++) {
        for (int k = 0; k < 8; k++) {
            const int j = k * 8 + wid;
            const int n = jn[j];
            if (n < 0) break;

            float agg = 0.f;
            if (use_lds) {
                const int4* ep = (const int4*)&eLDS[jofs[j]];   // 2 edges per int4
                const int pl = jplen[j];
                int e = 0;
                // 16 edges per iteration: 16 independent loads in flight
                for (; e + 16 <= pl; e += 16) {
                    int4 p0 = ep[0], p1 = ep[1], p2 = ep[2], p3 = ep[3];
                    int4 p4 = ep[4], p5 = ep[5], p6 = ep[6], p7 = ep[7];
                    ep += 8;
                    float v0 = *(const float*)(hprev + (hoffb + p0.x));
                    float v1 = *(const float*)(hprev + (hoffb + p0.z));
                    float v2 = *(const float*)(hprev + (hoffb + p1.x));
                    float v3 = *(const float*)(hprev + (hoffb + p1.z));
                    float v4 = *(const float*)(hprev + (hoffb + p2.x));
                    float v5 = *(const float*)(hprev + (hoffb + p2.z));
                    float v6 = *(const float*)(hprev + (hoffb + p3.x));
                    float v7 = *(const float*)(hprev + (hoffb + p3.z));
                    float v8 = *(const float*)(hprev + (hoffb + p4.x));
                    float v9 = *(const float*)(hprev + (hoffb + p4.z));
                    float va = *(const float*)(hprev + (hoffb + p5.x));
                    float vb = *(const float*)(hprev + (hoffb + p5.z));
                    float vc = *(const float*)(hprev + (hoffb + p6.x));
                    float vd = *(const float*)(hprev + (hoffb + p6.z));
                    float ve = *(const float*)(hprev + (hoffb + p7.x));
                    float vf = *(const float*)(hprev + (hoffb + p7.z));
                    agg = fmaf(__int_as_float(p0.y), v0, agg);
                    agg = fmaf(__int_as_float(p0.w), v1, agg);
                    agg = fmaf(__int_as_float(p1.y), v2, agg);
                    agg = fmaf(__int_as_float(p1.w), v3, agg);
                    agg = fmaf(__int_as_float(p2.y), v4, agg);
                    agg = fmaf(__int_as_float(p2.w), v5, agg);
                    agg = fmaf(__int_as_float(p3.y), v6, agg);
                    agg = fmaf(__int_as_float(p3.w), v7, agg);
                    agg = fmaf(__int_as_float(p4.y), v8, agg);
                    agg = fmaf(__int_as_float(p4.w), v9, agg);
                    agg = fmaf(__int_as_float(p5.y), va, agg);
                    agg = fmaf(__int_as_float(p5.w), vb, agg);
                    agg = fmaf(__int_as_float(p6.y), vc, agg);
                    agg = fmaf(__int_as_float(p6.w), vd, agg);
                    agg = fmaf(__int_as_float(p7.y), ve, agg);
                    agg = fmaf(__int_as_float(p7.w), vf, agg);
                }
                if (e < pl) {   // pl is a multiple of 8 -> at most one 8-chunk tail
                    int4 p0 = ep[0], p1 = ep[1], p2 = ep[2], p3 = ep[3];
                    float v0 = *(const float*)(hprev + (hoffb + p0.x));
                    float v1 = *(const float*)(hprev + (hoffb + p0.z));
                    float v2 = *(const float*)(hprev + (hoffb + p1.x));
                    float v3 = *(const float*)(hprev + (hoffb + p1.z));
                    float v4 = *(const float*)(hprev + (hoffb + p2.x));
                    float v5 = *(const float*)(hprev + (hoffb + p2.z));
                    float v6 = *(const float*)(hprev + (hoffb + p3.x));
                    float v7 = *(const float*)(hprev + (hoffb + p3.z));
                    agg = fmaf(__int_as_float(p0.y), v0, agg);
                    agg = fmaf(__int_as_float(p0.w), v1, agg);
                    agg = fmaf(__int_as_float(p1.y), v2, agg);
                    agg = fmaf(__int_as_float(p1.w), v3, agg);
                    agg = fmaf(__int_as_float(p2.y), v4, agg);
                    agg = fmaf(__int_as_float(p2.w), v5, agg);
                    agg = fmaf(__int_as_float(p3.y), v6, agg);
                    agg = fmaf(__int_as_float(p3.w), v7, agg);
                }
            } else {   // rare overflow path: stream from global
                const int rs = jrs[j], re = rs + jraw[j];
                for (int e = rs; e < re; e++) {
                    int cb = col_idx[e] << 2;
                    agg = fmaf(wgt[e], *(const float*)(hprev + (hoffb + cb)), agg);
                }
            }

            // matvec: conv[l] = bg[l] + sum_k agg[k] * Wg[k][l]
            // per-wave LDS broadcast (writer wave == reader wave -> lockstep)
            aggL[tid] = agg;
            const float4* arow = (const float4*)&aggL[(tid & ~63) + (half << 5)];
            float conv = bgv;
#pragma unroll
            for (int kq = 0; kq < 8; kq++) {
                float4 a4 = arow[kq];
                conv = fmaf(a4.x, wgreg[4 * kq + 0], conv);
                conv = fmaf(a4.y, wgreg[4 * kq + 1], conv);
                conv = fmaf(a4.z, wgreg[4 * kq + 2], conv);
                conv = fmaf(a4.w, wgreg[4 * kq + 3], conv);
            }

            const float r = fast_sigmoid(xrv + conv);
            const float z = fast_sigmoid(xzv + conv);
            const float e2 = __expf(2.f * (xhv + r * conv));
            const float ht = 1.f - 2.f * __builtin_amdgcn_rcpf(e2 + 1.f);
            const int nb = hoffb + (n << 7);             // node byte offset
            const float hp = *(const float*)(hprev + nb);
            const float hn = fmaf(z, ht - hp, hp);

            *(float*)(hnext + nb) = hn;
            __builtin_nontemporal_store(hn, outp + (n << 5));
        }
        if (t != SEQ - 1) {
            if (xmode) xcd_barrier(xcnt, xgo, xid, slot, cnt, (unsigned)(t + 1));
            else       global_barrier(glvl1, groot, (unsigned)(t + 2));
        }
        char* tmp = (char*)hprev; hprev = hnext; hnext = tmp;
        outp += NN * HD;
    }
}

// ---------------- launch ----------------

extern "C" void kernel_launch(void* const* d_in, const int* in_sizes, int n_in,
                              void* d_out, int out_size, void* d_ws, size_t ws_size,
                              hipStream_t stream) {
    const float* x   = (const float*)d_in[0];
    const int*   src = (const int*)d_in[1];
    const int*   dst = (const int*)d_in[2];
    const float* Wr  = (const float*)d_in[3];
    const float* br  = (const float*)d_in[4];
    const float* Wz  = (const float*)d_in[5];
    const float* bz  = (const float*)d_in[6];
    const float* Wh  = (const float*)d_in[7];
    const float* bh  = (const float*)d_in[8];
    const float* Wg  = (const float*)d_in[9];
    const float* bg  = (const float*)d_in[10];
    float* out = (float*)d_out;

    char* ws = (char*)d_ws;
    float* h0 = (float*)ws;            ws += (size_t)BATCH * NN * HD * 4;
    float* h1 = (float*)ws;            ws += (size_t)BATCH * NN * HD * 4;
    float* xr = (float*)ws;            ws += BATCH * HD * 4;
    float* xz = (float*)ws;            ws += BATCH * HD * 4;
    float* xh = (float*)ws;            ws += BATCH * HD * 4;
    int* deg_out = (int*)ws;           ws += NN * 4;
    int* deg_in  = (int*)ws;           ws += NN * 4;
    int* cursor  = (int*)ws;           ws += NN * 4;
    int* row_ptr = (int*)ws;           ws += (NN + 1) * 4;
    int* col_idx = (int*)ws;           ws += NE * 4;
    float* wgt   = (float*)ws;         ws += NE * 4;
    int* perm    = (int*)ws;           ws += NN * 4;
    unsigned* glvl1 = (unsigned*)ws;   ws += NGRP * 32 * 4;
    unsigned* groot = (unsigned*)ws;   ws += 32 * 4;
    unsigned* xreg  = (unsigned*)ws;   ws += NXCD * 32 * 4;
    unsigned* xcnt  = (unsigned*)ws;   ws += NXCD * 8 * 32 * 4;
    unsigned* xgo   = (unsigned*)ws;   ws += NXCD * 32 * 4;

    // t=0 shortcut never reads h -> no h memset needed; only barrier counters.
    hipMemsetAsync(deg_out, 0, 3 * NN * 4, stream);
    hipMemsetAsync(glvl1, 0,
                   (NGRP * 32 + 32 + NXCD * 32 + NXCD * 8 * 32 + NXCD * 32) * 4, stream);

    count_deg<<<NE / 256, 256, 0, stream>>>(src, dst, deg_out, deg_in);
    scan_rowptr<<<1, 256, 0, stream>>>(deg_in, row_ptr);
    build_perm<<<1, 256, 0, stream>>>(deg_in, perm);
    scatter_edges<<<NE / 256, 256, 0, stream>>>(src, dst, deg_out, deg_in, row_ptr,
                                                cursor, col_idx, wgt);
    xgates<<<2, 256, 0, stream>>>(x, Wr, br, Wz, bz, Wh, bh, xr, xz, xh);

    gru_persistent<<<dim3(NBLK), dim3(TPB), 0, stream>>>(
        h0, h1, row_ptr, col_idx, wgt, perm, Wg, bg, xr, xz, xh, out,
        glvl1, groot, xreg, xcnt, xgo);
}